// Round 6
// baseline (200.993 us; speedup 1.0000x reference)
//
#include <hip/hip_runtime.h>
#include <hip/hip_bf16.h>
#include <hip/hip_fp16.h>

// ---------------------------------------------------------------------------
// 2-layer GCN (PyG GCNConv semantics):
//   deg[i]  = in-degree(i) + 1 (self loop);  dinv = rsqrt(deg)
//   hs      = (x @ W) * dinv[row]        (stored fp16)
//   out[d]  = dinv[d] * ( sum_{(s,d) in E} hs[s] + hs[d] ) + b    (+ relu L1)
//
// Round 5 evidence: scatter_k 42.5us @ 8.9% occupancy, VALU 0.6% -> it was
// latency-bound at 256 blocks (1 block/CU), not bandwidth-bound. Round 6:
// 2048 blocks for hist/scatter (32 waves/CU), hist_k goes edge-parallel with
// direct global atomics (LDS flush would cost more than the edges at 2048
// blocks), and the graph-internal hipMemsetAsync is replaced by zero_k.
// Bucket privatization per (dst>>6, blockIdx&7) unchanged.
// ---------------------------------------------------------------------------

#define NBUCK 800           // buckets of 64 nodes: covers 51200 >= N
#define NSEG  (NBUCK * 8)   // per-(bucket, blockIdx&7) segments
#define EBLK  2048          // blocks for hist/scatter (chunking must match!)

__global__ __launch_bounds__(256) void zero_k(int* __restrict__ p, int n) {
    int i = blockIdx.x * 256 + threadIdx.x;
    if (i < n) p[i] = 0;
}

__global__ __launch_bounds__(256) void hist_k(const int* __restrict__ dst,
                                              int* __restrict__ hist,
                                              int E, int chunk) {
    int k = blockIdx.x & 7;
    int lo = blockIdx.x * chunk, hi = min(E, lo + chunk);
    for (int e = lo + threadIdx.x; e < hi; e += 256)
        atomicAdd(&hist[(dst[e] >> 6) * 8 + k], 1);
}

// One block: exclusive scan of NSEG=6400 segment counts (25 per thread).
// Also writes segBase[NSEG]=E and offsets[N]=E.
__global__ __launch_bounds__(256) void scan_k(const int* __restrict__ hist,
                                              int* __restrict__ segBase,
                                              int* __restrict__ offsets,
                                              int N, int E) {
    __shared__ int sdata[256];
    int t = threadIdx.x;
    int base = t * 25;
    int v[25];
    int s = 0;
#pragma unroll
    for (int i = 0; i < 25; ++i) { int c = hist[base + i]; v[i] = c; s += c; }
    sdata[t] = s;
    __syncthreads();
#pragma unroll
    for (int off = 1; off < 256; off <<= 1) {
        int x = 0;
        if (t >= off) x = sdata[t - off];
        __syncthreads();
        sdata[t] += x;
        __syncthreads();
    }
    int run = sdata[t] - s;  // exclusive prefix
#pragma unroll
    for (int i = 0; i < 25; ++i) { segBase[base + i] = run; run += v[i]; }
    if (t == 255) segBase[NSEG] = run;  // == E
    if (t == 0) offsets[N] = E;
}

__global__ __launch_bounds__(256) void scatter_k(const int* __restrict__ src,
                                                 const int* __restrict__ dst,
                                                 const int* __restrict__ segBase,
                                                 int* __restrict__ gcur,
                                                 unsigned* __restrict__ rec,
                                                 int E, int chunk) {
    int k = blockIdx.x & 7;
    int lo = blockIdx.x * chunk, hi = min(E, lo + chunk);
    for (int e = lo + threadIdx.x; e < hi; e += 256) {
        int d = dst[e];
        int seg = (d >> 6) * 8 + k;
        int pos = atomicAdd(&gcur[seg], 1);
        rec[segBase[seg] + pos] = (unsigned)(src[e] & 0xffff) | ((unsigned)d << 16);
    }
}

// One block per bucket: per-node counts (LDS), dinv, offsets, u16 CSR adj.
__global__ __launch_bounds__(256) void finish_k(const unsigned* __restrict__ rec,
                                                const int* __restrict__ segBase,
                                                int* __restrict__ offsets,
                                                float* __restrict__ dinv,
                                                unsigned short* __restrict__ adj,
                                                int N) {
    __shared__ int ncnt[64], ncur[64], nodeOff[64];
    int b = blockIdx.x;
    int t = threadIdx.x;
    int segStart = segBase[b * 8];
    int segEnd = segBase[(b + 1) * 8];

    if (t < 64) { ncnt[t] = 0; ncur[t] = 0; }
    __syncthreads();

    for (int e = segStart + t; e < segEnd; e += 256)
        atomicAdd(&ncnt[(rec[e] >> 16) & 63], 1);
    __syncthreads();

    if (t == 0) {
        int r = 0;
#pragma unroll
        for (int i = 0; i < 64; ++i) { nodeOff[i] = r; r += ncnt[i]; }
    }
    __syncthreads();

    if (t < 64) {
        int gnode = b * 64 + t;
        if (gnode < N) {
            dinv[gnode] = rsqrtf((float)(ncnt[t] + 1));
            offsets[gnode] = segStart + nodeOff[t];
        }
    }
    __syncthreads();

    for (int e = segStart + t; e < segEnd; e += 256) {
        unsigned r = rec[e];
        int ln = (r >> 16) & 63;
        int p = atomicAdd(&ncur[ln], 1);
        adj[segStart + nodeOff[ln] + p] = (unsigned short)(r & 0xffff);
    }
}

// GEMM: Hout[row][c] = (half) dinv[row] * sum_k X[row][k] * W[k][c]
// Block: 256 threads, BM=64 rows, full K=128 in LDS, 4-col x ROWS register tile.
template <int NOUT, bool HALF_IN>
__global__ __launch_bounds__(256) void gemm_scale_k(const void* __restrict__ Xv,
                                                    const float* __restrict__ W,
                                                    const float* __restrict__ dinv,
                                                    __half* __restrict__ Hout, int M) {
    constexpr int K = 128;
    constexpr int BM = 64;
    constexpr int COLCH = NOUT / 4;    // float4 column chunks: 32 or 16
    constexpr int RG = 256 / COLCH;    // row groups: 8 or 16
    constexpr int ROWS = BM / RG;      // rows per thread: 8 or 4
    __shared__ float xs[BM][K];

    int t = threadIdx.x;
    int brow = blockIdx.x * BM;

    if constexpr (HALF_IN) {
        const __half* X = (const __half*)Xv;
        for (int i = t; i < BM * (K / 8); i += 256) {
            int row = i / (K / 8);
            int c8 = i % (K / 8);
            int gr = brow + row;
            float f[8] = {0.f, 0.f, 0.f, 0.f, 0.f, 0.f, 0.f, 0.f};
            if (gr < M) {
                uint4 u = *(const uint4*)(X + (size_t)gr * K + c8 * 8);
                const __half2* hp = (const __half2*)&u;
#pragma unroll
                for (int j = 0; j < 4; ++j) {
                    float2 fj = __half22float2(hp[j]);
                    f[2 * j] = fj.x;
                    f[2 * j + 1] = fj.y;
                }
            }
#pragma unroll
            for (int j = 0; j < 8; ++j) xs[row][c8 * 8 + j] = f[j];
        }
    } else {
        const float* X = (const float*)Xv;
        for (int i = t; i < BM * (K / 4); i += 256) {
            int row = i / (K / 4);
            int c4 = i % (K / 4);
            float4 v = make_float4(0.f, 0.f, 0.f, 0.f);
            int gr = brow + row;
            if (gr < M) v = *(const float4*)(X + (size_t)gr * K + c4 * 4);
            *(float4*)(&xs[row][c4 * 4]) = v;
        }
    }
    __syncthreads();

    int cc = t % COLCH;
    int rg = t / COLCH;

    float acc[ROWS][4];
#pragma unroll
    for (int r = 0; r < ROWS; ++r) {
        acc[r][0] = 0.f; acc[r][1] = 0.f; acc[r][2] = 0.f; acc[r][3] = 0.f;
    }

    for (int k4 = 0; k4 < K / 4; ++k4) {
        float4 xv[ROWS];
#pragma unroll
        for (int r = 0; r < ROWS; ++r)
            xv[r] = *(const float4*)(&xs[rg * ROWS + r][k4 * 4]);
#pragma unroll
        for (int kk = 0; kk < 4; ++kk) {
            float4 w = *(const float4*)(W + (size_t)(k4 * 4 + kk) * NOUT + cc * 4);
#pragma unroll
            for (int r = 0; r < ROWS; ++r) {
                float xvk = ((const float*)&xv[r])[kk];
                acc[r][0] += xvk * w.x;
                acc[r][1] += xvk * w.y;
                acc[r][2] += xvk * w.z;
                acc[r][3] += xvk * w.w;
            }
        }
    }

#pragma unroll
    for (int r = 0; r < ROWS; ++r) {
        int gr = brow + rg * ROWS + r;
        if (gr < M) {
            float s = dinv[gr];
            union { __half2 h[2]; uint2 u; } pk;
            pk.h[0] = __floats2half2_rn(acc[r][0] * s, acc[r][1] * s);
            pk.h[1] = __floats2half2_rn(acc[r][2] * s, acc[r][3] * s);
            *(uint2*)(Hout + (size_t)gr * NOUT + cc * 4) = pk.u;
        }
    }
}

// fp16 row-fragment loaders: 32 lanes cover one row.
__device__ __forceinline__ void ld_row(const __half* p, float (&f)[4]) {
    uint2 u = *(const uint2*)p;                    // 4 halves, 8B
    const __half2* hp = (const __half2*)&u;
    float2 a = __half22float2(hp[0]);
    float2 b = __half22float2(hp[1]);
    f[0] = a.x; f[1] = a.y; f[2] = b.x; f[3] = b.y;
}
__device__ __forceinline__ void ld_row(const __half* p, float (&f)[2]) {
    float2 a = __half22float2(*(const __half2*)p); // 2 halves, 4B
    f[0] = a.x; f[1] = a.y;
}

// Pull aggregation: 2 nodes per wave (one per 32-lane half-wave), 8-deep
// gather unroll => up to 16 rows in flight per wave. V = C/32 halves/lane.
template <int C, bool RELU, typename TOUT>
__global__ __launch_bounds__(256) void aggregate_k(const __half* __restrict__ H,
                                                   const int* __restrict__ offsets,
                                                   const unsigned short* __restrict__ adj,
                                                   const float* __restrict__ dinv,
                                                   const float* __restrict__ bias,
                                                   TOUT* __restrict__ out, int n) {
    constexpr int V = C / 32;
    int wave = threadIdx.x >> 6;
    int lane = threadIdx.x & 63;
    int half_id = lane >> 5;
    int sub = lane & 31;
    int node = blockIdx.x * 8 + wave * 2 + half_id;
    if (node >= n) return;

    const __half* hl = H + sub * V;  // lane-fragment base

    float acc[V];
    ld_row(hl + (size_t)node * C, acc);  // self-loop term hs[node]

    int e0 = offsets[node], e1 = offsets[node + 1];
    int e = e0;

    // main: 8 edges per iter, 8 row-gathers outstanding (x2 nodes per wave)
    for (; e + 8 <= e1; e += 8) {
        int s[8];
#pragma unroll
        for (int j = 0; j < 8; ++j) s[j] = adj[e + j];
        float t[8][V];
#pragma unroll
        for (int j = 0; j < 8; ++j) ld_row(hl + (size_t)s[j] * C, t[j]);
#pragma unroll
        for (int v = 0; v < V; ++v)
            acc[v] += ((t[0][v] + t[1][v]) + (t[2][v] + t[3][v])) +
                      ((t[4][v] + t[5][v]) + (t[6][v] + t[7][v]));
    }
    for (; e + 2 <= e1; e += 2) {
        int s0 = adj[e], s1 = adj[e + 1];
        float t0[V], t1[V];
        ld_row(hl + (size_t)s0 * C, t0);
        ld_row(hl + (size_t)s1 * C, t1);
#pragma unroll
        for (int v = 0; v < V; ++v) acc[v] += t0[v] + t1[v];
    }
    if (e < e1) {
        float t0[V];
        ld_row(hl + (size_t)adj[e] * C, t0);
#pragma unroll
        for (int v = 0; v < V; ++v) acc[v] += t0[v];
    }

    float di = dinv[node];
    float o[V];
#pragma unroll
    for (int v = 0; v < V; ++v) {
        o[v] = acc[v] * di + bias[sub * V + v];
        if (RELU) o[v] = fmaxf(o[v], 0.f);
    }

    if constexpr (sizeof(TOUT) == 2) {  // __half output (hidden layer), V==4
        union { __half2 h[2]; uint2 u; } pk;
        pk.h[0] = __floats2half2_rn(o[0], o[1]);
        pk.h[1] = __floats2half2_rn(o[2], o[3]);
        *(uint2*)((__half*)out + (size_t)node * C + sub * V) = pk.u;
    } else {  // float output (final), V==2
        *(float2*)((float*)out + (size_t)node * C + sub * V) = make_float2(o[0], o[1]);
    }
}

extern "C" void kernel_launch(void* const* d_in, const int* in_sizes, int n_in,
                              void* d_out, int out_size, void* d_ws, size_t ws_size,
                              hipStream_t stream) {
    const float* x = (const float*)d_in[0];
    const int* ei = (const int*)d_in[1];   // harness passes integers as int32
    const float* W1 = (const float*)d_in[2];
    const float* b1 = (const float*)d_in[3];
    const float* W2 = (const float*)d_in[4];
    const float* b2 = (const float*)d_in[5];
    float* out = (float*)d_out;

    const int IN_C = 128, HID_C = 128;
    int N = in_sizes[0] / IN_C;   // 50000
    int E = in_sizes[1] / 2;      // 800000
    const int* src = ei;          // row 0
    const int* dst = ei + E;      // row 1

    // --- workspace layout ---
    int NP = (N + 255) & ~255;
    int EP = (E + 255) & ~255;
    char* w = (char*)d_ws;
    int* hist = (int*)w;            w += (size_t)NSEG * 4;       // zeroed
    int* gcur = (int*)w;            w += (size_t)NSEG * 4;       // zeroed (contig w/ hist)
    int* segBase = (int*)w;         w += (size_t)(NSEG + 256) * 4;
    int* offsets = (int*)w;         w += (size_t)(NP + 256) * 4;
    float* dinv = (float*)w;        w += (size_t)NP * 4;
    unsigned* rec = (unsigned*)w;   w += (size_t)EP * 4;
    unsigned short* adj = (unsigned short*)w; w += (size_t)EP * 2;
    __half* H1 = (__half*)w;        w += (size_t)NP * HID_C * 2;  // hs1 / hs2 (fp16)
    __half* HID = (__half*)w;       w += (size_t)NP * HID_C * 2;  // relu'd hidden (fp16)
    (void)ws_size; (void)n_in; (void)out_size;

    int chunk = (E + EBLK - 1) / EBLK;  // identical chunking for hist & scatter

    // hist + gcur contiguous: one kernel zeros both (keep fillBuffer out of graph).
    zero_k<<<(NSEG * 2 + 255) / 256, 256, 0, stream>>>(hist, NSEG * 2);

    hist_k<<<EBLK, 256, 0, stream>>>(dst, hist, E, chunk);
    scan_k<<<1, 256, 0, stream>>>(hist, segBase, offsets, N, E);
    scatter_k<<<EBLK, 256, 0, stream>>>(src, dst, segBase, gcur, rec, E, chunk);
    finish_k<<<NBUCK, 256, 0, stream>>>(rec, segBase, offsets, dinv, adj, N);

    // Layer 1: hs1 = fp16((x @ W1) * dinv) ; HID = fp16(relu(dinv*gather + b1))
    gemm_scale_k<128, false><<<(N + 63) / 64, 256, 0, stream>>>(x, W1, dinv, H1, N);
    aggregate_k<128, true, __half><<<(N + 7) / 8, 256, 0, stream>>>(
        H1, offsets, adj, dinv, b1, HID, N);

    // Layer 2: hs2 = fp16((HID @ W2) * dinv) ; out = fp32(dinv*gather + b2)
    gemm_scale_k<64, true><<<(N + 63) / 64, 256, 0, stream>>>(HID, W2, dinv, H1, N);
    aggregate_k<64, false, float><<<(N + 7) / 8, 256, 0, stream>>>(
        H1, offsets, adj, dinv, b2, out, N);
}